// Round 13
// baseline (56.991 us; speedup 1.0000x reference)
//
#include <hip/hip_runtime.h>
#include <math.h>

#define Bn 32
#define Ln 524288
#define NF 4

#define TPB   256               // 4 waves
#define NW    (TPB / 64)        // 4
#define CPT   18                // samples per thread (9 float2)
#define OUT   4096              // output samples per WG-tile
#define WU    512               // warm-up samples
#define S_WG  (OUT + WU)        // 4608
#define TPR   (Ln / OUT)        // 128 tiles per row
#define NTILE 2                 // tiles per WG (software pipeline depth)
#define NT    (Bn * TPR / NTILE)// 2048 WGs -> 8 per CU, single generation

#define SLOT4  (S_WG / 4)       // 1152 float4 slots
#define OSLOT4 (OUT / 4)        // 1024
#define WSLOT4 (WU / 4)         // 128

// ws layout (float indices)
#define COEF_OFF 0               // 20
#define POWJ_OFF 64              // j=0..5: A^(18*2^j)      (384)
#define XW1_OFF  448             // A^1152 (wave span)      (64)
#define PLM4_OFF 512             // packed PLM[l]=A^(18l): 10 grp x 64 lane x f4 (2560)
#define WSEQ_OFF 3072            // w_n = C*A^n: 18 x 8     (144)

// LDS: identity float4/float2 slots + wave aggregates
#define WAGG_L (SLOT4 * 4)       // float idx: 4 waves * 8
#define LDS_F  (WAGG_L + 32)     // 4640 floats = 18.6 KB -> 8 WG/CU

// packed block-lower-triangular index maps (rows use cols 0..(r|1))
__device__ __forceinline__ constexpr int prow(int p) {
    return (p < 2) ? 0 : (p < 4) ? 1 : (p < 8) ? 2 : (p < 12) ? 3
         : (p < 18) ? 4 : (p < 24) ? 5 : (p < 32) ? 6 : 7;
}
__device__ __forceinline__ constexpr int pcol(int p) {
    return p - ((p < 2) ? 0 : (p < 4) ? 2 : (p < 8) ? 4 : (p < 12) ? 8
              : (p < 18) ? 12 : (p < 24) ? 18 : (p < 32) ? 24 : 32);
}

// ---------------------------------------------------------------------------
// Precompute (1 block, 64 thr): coefs; unit-state sim (double) -> A^18 cols
// and w_n = C*A^n rows; squaring chain A^(18*2^j), XW1 = A^1152; PLM[l] =
// A^(18l) via per-thread binary decomposition.
// ---------------------------------------------------------------------------
__global__ void precompute_k(const float* __restrict__ lr,
                             const float* __restrict__ ra,
                             const float* __restrict__ b0,
                             const float* __restrict__ b1,
                             const float* __restrict__ b2,
                             float* __restrict__ ws) {
    __shared__ double A2d[6][64];
    __shared__ float  A2f[6][64];
    __shared__ double Tw[64];
    const int t = threadIdx.x;  // 64

    if (t < NF) {
        double r   = 0.999 / (1.0 + exp(-(double)lr[t]));
        double ang = 3.14159265358979323846 / (1.0 + exp(-(double)ra[t]));
        ws[COEF_OFF + t * 5 + 0] = b0[t];
        ws[COEF_OFF + t * 5 + 1] = b1[t];
        ws[COEF_OFF + t * 5 + 2] = b2[t];
        ws[COEF_OFF + t * 5 + 3] = (float)(-2.0 * r * cos(ang));
        ws[COEF_OFF + t * 5 + 4] = (float)(r * r);
    }
    __syncthreads();

    if (t < 8) {
        double cb0[NF], cb1[NF], cb2[NF], ca1[NF], ca2[NF];
        for (int f = 0; f < NF; ++f) {
            cb0[f] = (double)ws[COEF_OFF + f * 5 + 0];
            cb1[f] = (double)ws[COEF_OFF + f * 5 + 1];
            cb2[f] = (double)ws[COEF_OFF + f * 5 + 2];
            ca1[f] = (double)ws[COEF_OFF + f * 5 + 3];
            ca2[f] = (double)ws[COEF_OFF + f * 5 + 4];
        }
        double s[8];
        for (int r = 0; r < 8; ++r) s[r] = 0.0;
        s[t] = 1.0;
        for (int n = 0; n < CPT; ++n) {
            double v = 0.0;  // zero input
            for (int f = 0; f < NF; ++f) {
                double y     = cb0[f] * v + s[2 * f];
                s[2 * f]     = cb1[f] * v - ca1[f] * y + s[2 * f + 1];
                s[2 * f + 1] = cb2[f] * v - ca2[f] * y;
                v = y;
            }
            ws[WSEQ_OFF + n * 8 + t] = (float)v;  // w_n[t]
        }
        for (int r = 0; r < 8; ++r) A2d[0][r * 8 + t] = s[r];  // col t of A^18
    }
    __syncthreads();

    A2f[0][t] = (float)A2d[0][t];
    ws[POWJ_OFF + t] = A2f[0][t];
    const int r8 = t >> 3, c8 = t & 7;
    for (int j = 1; j <= 6; ++j) {
        const double* S = A2d[j - 1];
        double acc = 0.0;
        for (int m = 0; m < 8; ++m) acc += S[r8 * 8 + m] * S[m * 8 + c8];
        Tw[t] = acc;
        __syncthreads();
        if (j <= 5) {
            A2d[j][t] = Tw[t];
            A2f[j][t] = (float)Tw[t];
            ws[POWJ_OFF + j * 64 + t] = (float)Tw[t];
        } else {
            ws[XW1_OFF + t] = (float)Tw[t];  // A^1152
        }
        __syncthreads();
    }

    // PLM[t] = A^(18*t) via binary decomposition
    float M[64];
#pragma unroll
    for (int i = 0; i < 64; ++i) M[i] = ((i >> 3) == (i & 7)) ? 1.f : 0.f;
    for (int j = 0; j < 6; ++j) {
        if ((t >> j) & 1) {
            float Tn[64];
            for (int r = 0; r < 8; ++r)
                for (int c = 0; c < 8; ++c) {
                    float acc = 0.f;
                    for (int m = 0; m < 8; ++m)
                        acc = fmaf(M[r * 8 + m], A2f[j][m * 8 + c], acc);
                    Tn[r * 8 + c] = acc;
                }
            for (int i = 0; i < 64; ++i) M[i] = Tn[i];
        }
    }
    for (int p = 0; p < 40; ++p)
        ws[PLM4_OFF + (p >> 2) * 256 + t * 4 + (p & 3)] = M[prow(p) * 8 + pcol(p)];
}

// ---------------------------------------------------------------------------
__device__ __forceinline__ void step1(float& u, float* s,
                                      const float* c0, const float* c1,
                                      const float* c2, const float* A1,
                                      const float* A2) {
#pragma unroll
    for (int f = 0; f < NF; ++f) {
        float yv     = fmaf(c0[f], u, s[2 * f]);
        s[2 * f]     = fmaf(-A1[f], yv, fmaf(c1[f], u, s[2 * f + 1]));
        s[2 * f + 1] = fmaf(-A2[f], yv, c2[f] * u);
        u = yv;
    }
}

__device__ __forceinline__ void matvec_acc_sp(float* o, const float* __restrict__ T,
                                              const float* p) {
#pragma unroll
    for (int r = 0; r < 8; ++r) {
        const int ncol = (r | 1) + 1;
#pragma unroll
        for (int c = 0; c < 8; ++c)
            if (c < ncol) o[r] = fmaf(T[r * 8 + c], p[c], o[r]);
    }
}
__device__ __forceinline__ void matvec_rep_sp(float* h, const float* __restrict__ T) {
    float tmp[8];
#pragma unroll
    for (int r = 0; r < 8; ++r) {
        const int ncol = (r | 1) + 1;
        float acc = 0.f;
#pragma unroll
        for (int c = 0; c < 8; ++c)
            if (c < ncol) acc = fmaf(T[r * 8 + c], h[c], acc);
        tmp[r] = acc;
    }
#pragma unroll
    for (int r = 0; r < 8; ++r) h[r] = tmp[r];
}

// ---------------------------------------------------------------------------
// Persistent-ish: one WG = NTILE consecutive 4096-sample tiles, software-
// pipelined (tile k+1's global loads issued before tile k's compute).
// ---------------------------------------------------------------------------
__global__ __launch_bounds__(TPB, 8) void biquad_k(const float* __restrict__ x,
                                                   const float* __restrict__ ws,
                                                   float* __restrict__ y) {
    __shared__ __align__(16) float ldsf[LDS_F];
    float4* lds4 = (float4*)ldsf;
    float2* lds2 = (float2*)ldsf;
    const int t    = threadIdx.x;
    const int lane = t & 63;
    const int w    = t >> 6;

    const float* __restrict__ mats = ws + POWJ_OFF;
    const float* __restrict__ xw1  = ws + XW1_OFF;
    const float4* xg4 = (const float4*)x;
    float4* yg4 = (float4*)y;

    float c0[NF], c1[NF], c2[NF], A1[NF], A2[NF];
#pragma unroll
    for (int f = 0; f < NF; ++f) {
        c0[f] = ws[COEF_OFF + f * 5 + 0];
        c1[f] = ws[COEF_OFF + f * 5 + 1];
        c2[f] = ws[COEF_OFF + f * 5 + 2];
        A1[f] = ws[COEF_OFF + f * 5 + 3];
        A2[f] = ws[COEF_OFF + f * 5 + 4];
    }

    // ---- prologue: prefetch tile 0 into regs ----
    float4 pf[5];
    {
        const int tile = blockIdx.x * NTILE;
        const int tpos = tile % TPR;
        const long base4 = (long)(tile / TPR) * (Ln / 4) + (long)tpos * OSLOT4 - WSLOT4;
#pragma unroll
        for (int j = 0; j < 5; ++j) {
            const int n4 = j * TPB + t;
            pf[j] = make_float4(0.f, 0.f, 0.f, 0.f);
            if (n4 < SLOT4 && (tpos > 0 || n4 >= WSLOT4)) pf[j] = xg4[base4 + n4];
        }
    }

#pragma unroll
    for (int k = 0; k < NTILE; ++k) {
        const int tile = blockIdx.x * NTILE + k;
        const int row  = tile / TPR;
        const int tpos = tile % TPR;

        if (k > 0) __syncthreads();  // prior output reads done before overwrite

        // ---- stage regs -> LDS ----
#pragma unroll
        for (int j = 0; j < 5; ++j) {
            const int n4 = j * TPB + t;
            if (n4 < SLOT4) lds4[n4] = pf[j];
        }
        __syncthreads();

        // ---- issue next tile's loads NOW (drain under this tile's compute) ----
        if (k + 1 < NTILE) {
            const int ntile = tile + 1;
            const int ntpos = ntile % TPR;
            const long nbase4 = (long)(ntile / TPR) * (Ln / 4) + (long)ntpos * OSLOT4 - WSLOT4;
#pragma unroll
            for (int j = 0; j < 5; ++j) {
                const int n4 = j * TPB + t;
                float4 v = make_float4(0.f, 0.f, 0.f, 0.f);
                if (n4 < SLOT4 && (ntpos > 0 || n4 >= WSLOT4)) v = xg4[nbase4 + n4];
                pf[j] = v;
            }
        }

        // ---- pass 1: preload own chunk, filter, write y0 back in place ----
        float s[8];
#pragma unroll
        for (int r = 0; r < 8; ++r) s[r] = 0.f;
        {
            float2 xr[CPT / 2];
#pragma unroll
            for (int i = 0; i < CPT / 2; ++i) xr[i] = lds2[(CPT / 2) * t + i];
#pragma unroll
            for (int i = 0; i < CPT / 2; ++i) {
                float u;
                u = xr[i].x; step1(u, s, c0, c1, c2, A1, A2); xr[i].x = u;
                u = xr[i].y; step1(u, s, c0, c1, c2, A1, A2); xr[i].y = u;
            }
#pragma unroll
            for (int i = 0; i < CPT / 2; ++i) lds2[(CPT / 2) * t + i] = xr[i];
        }

        // ---- intra-wave affine Kogge-Stone over 64 chunks ----
        float v8[8];
#pragma unroll
        for (int r = 0; r < 8; ++r) v8[r] = s[r];
#pragma unroll
        for (int j = 0; j < 6; ++j) {
            const int st = 1 << j;
            float p[8];
#pragma unroll
            for (int r = 0; r < 8; ++r) p[r] = __shfl_up(v8[r], st, 64);
            if (lane >= st) matvec_acc_sp(v8, mats + j * 64, p);
        }

        if (lane == 63) {
#pragma unroll
            for (int r = 0; r < 8; ++r) ldsf[WAGG_L + w * 8 + r] = v8[r];
        }
        __syncthreads();

        // ---- wave entry H (redundant per-thread Horner, oldest-first) ----
        float H[8];
#pragma unroll
        for (int r = 0; r < 8; ++r) H[r] = 0.f;
#pragma unroll
        for (int m = 0; m < NW - 1; ++m) {
            if (m < w) {
                matvec_rep_sp(H, xw1);
#pragma unroll
                for (int r = 0; r < 8; ++r) H[r] += ldsf[WAGG_L + m * 8 + r];
            }
        }

        // ---- delta = PLM[lane]*H + v8[lane-1] ----
        float dlt[8];
#pragma unroll
        for (int r = 0; r < 8; ++r) dlt[r] = 0.f;
        {
            const float4* plm4 = (const float4*)(ws + PLM4_OFF);
#pragma unroll
            for (int g = 0; g < 10; ++g) {
                const float4 mv = plm4[g * 64 + lane];
                dlt[prow(4 * g + 0)] = fmaf(mv.x, H[pcol(4 * g + 0)], dlt[prow(4 * g + 0)]);
                dlt[prow(4 * g + 1)] = fmaf(mv.y, H[pcol(4 * g + 1)], dlt[prow(4 * g + 1)]);
                dlt[prow(4 * g + 2)] = fmaf(mv.z, H[pcol(4 * g + 2)], dlt[prow(4 * g + 2)]);
                dlt[prow(4 * g + 3)] = fmaf(mv.w, H[pcol(4 * g + 3)], dlt[prow(4 * g + 3)]);
            }
        }
#pragma unroll
        for (int r = 0; r < 8; ++r) {
            const float pv = __shfl_up(v8[r], 1, 64);
            if (lane > 0) dlt[r] += pv;
        }

        // ---- correction: y_n = y0_n + w_n . delta (reload y0, write back) ----
        const float* __restrict__ wsq = ws + WSEQ_OFF;
#pragma unroll
        for (int i = 0; i < CPT / 2; ++i) {
            float2 v = lds2[(CPT / 2) * t + i];
            float a0 = 0.f, a1 = 0.f;
#pragma unroll
            for (int kk = 0; kk < 8; ++kk) {
                a0 = fmaf(wsq[(2 * i) * 8 + kk], dlt[kk], a0);
                a1 = fmaf(wsq[(2 * i + 1) * 8 + kk], dlt[kk], a1);
            }
            v.x += a0;
            v.y += a1;
            lds2[(CPT / 2) * t + i] = v;
        }
        __syncthreads();

        // ---- coalesced write of output region ----
        const long obase4 = (long)row * (Ln / 4) + (long)tpos * OSLOT4;
#pragma unroll
        for (int j = 0; j < 4; ++j) {
            const int n4 = WSLOT4 + j * TPB + t;  // [128, 1152)
            yg4[obase4 + (n4 - WSLOT4)] = lds4[n4];
        }
    }
}

// ---------------------------------------------------------------------------
extern "C" void kernel_launch(void* const* d_in, const int* in_sizes, int n_in,
                              void* d_out, int out_size, void* d_ws, size_t ws_size,
                              hipStream_t stream) {
    const float* x  = (const float*)d_in[0];
    const float* lr = (const float*)d_in[1];
    const float* ra = (const float*)d_in[2];
    const float* b0 = (const float*)d_in[3];
    const float* b1 = (const float*)d_in[4];
    const float* b2 = (const float*)d_in[5];
    float* y  = (float*)d_out;
    float* ws = (float*)d_ws;

    precompute_k<<<dim3(1), dim3(64), 0, stream>>>(lr, ra, b0, b1, b2, ws);
    biquad_k<<<dim3(NT), dim3(TPB), 0, stream>>>(x, ws, y);
}

// Round 14
// 49.201 us; speedup vs baseline: 1.1583x; 1.1583x over previous
//
#include <hip/hip_runtime.h>
#include <math.h>

#define Bn 32
#define Ln 524288
#define NF 4

#define OUT    2048              // output samples per wave-tile
#define WU     512               // warm-up samples (entry state = 0 exactly)
#define TILE   (OUT + WU)        // 2560
#define CPT    (TILE / 64)       // 40 samples per lane
#define TPR    (Ln / OUT)        // 256 tiles per row
#define NTILES (Bn * TPR)        // 8192
#define WPB    2                 // independent waves per block
#define TPB    (WPB * 64)        // 128
#define NBLK   (NTILES / WPB)    // 4096 blocks

// ws layout (float indices)
#define COEF_OFF 0               // 20
#define POWJ_OFF 64              // j=0..5: A^(40*2^j)  (384)
#define WSEQ_OFF 512             // w_n = C*A^n, n=0..39: 40x8 (320)

#define CSTR    42               // padded per-lane chunk stride (floats, even)
#define SLICE_F (64 * CSTR)      // 2688 floats per wave slice

// ---------------------------------------------------------------------------
// Precompute (1 block, 64 thr): f32-rounded coefs; unit-state sim (double)
// over 40 steps -> w_n rows and A^40 columns; squaring chain A^(40*2^j) j<=5.
// ---------------------------------------------------------------------------
__global__ void precompute_k(const float* __restrict__ lr,
                             const float* __restrict__ ra,
                             const float* __restrict__ b0,
                             const float* __restrict__ b1,
                             const float* __restrict__ b2,
                             float* __restrict__ ws) {
    __shared__ double Md[64], Td[64];
    const int t = threadIdx.x;

    if (t < NF) {
        double r   = 0.999 / (1.0 + exp(-(double)lr[t]));
        double ang = 3.14159265358979323846 / (1.0 + exp(-(double)ra[t]));
        ws[COEF_OFF + t * 5 + 0] = b0[t];
        ws[COEF_OFF + t * 5 + 1] = b1[t];
        ws[COEF_OFF + t * 5 + 2] = b2[t];
        ws[COEF_OFF + t * 5 + 3] = (float)(-2.0 * r * cos(ang));
        ws[COEF_OFF + t * 5 + 4] = (float)(r * r);
    }
    __syncthreads();

    if (t < 8) {
        double cb0[NF], cb1[NF], cb2[NF], ca1[NF], ca2[NF];
        for (int f = 0; f < NF; ++f) {
            cb0[f] = (double)ws[COEF_OFF + f * 5 + 0];
            cb1[f] = (double)ws[COEF_OFF + f * 5 + 1];
            cb2[f] = (double)ws[COEF_OFF + f * 5 + 2];
            ca1[f] = (double)ws[COEF_OFF + f * 5 + 3];
            ca2[f] = (double)ws[COEF_OFF + f * 5 + 4];
        }
        double s[8];
        for (int r = 0; r < 8; ++r) s[r] = 0.0;
        s[t] = 1.0;  // unit state e_t, zero input
        for (int n = 0; n < CPT; ++n) {
            double v = 0.0;
            for (int f = 0; f < NF; ++f) {
                double y     = cb0[f] * v + s[2 * f];
                s[2 * f]     = cb1[f] * v - ca1[f] * y + s[2 * f + 1];
                s[2 * f + 1] = cb2[f] * v - ca2[f] * y;
                v = y;
            }
            ws[WSEQ_OFF + n * 8 + t] = (float)v;  // w_n[t]
        }
        for (int r = 0; r < 8; ++r) Md[r * 8 + t] = s[r];  // col t of A^40
    }
    __syncthreads();

    ws[POWJ_OFF + t] = (float)Md[t];  // j=0: A^40
    const int r8 = t >> 3, c8 = t & 7;
    for (int sq = 1; sq <= 5; ++sq) {
        double acc = 0.0;
        for (int m = 0; m < 8; ++m) acc += Md[r8 * 8 + m] * Md[m * 8 + c8];
        Td[t] = acc;
        __syncthreads();
        Md[t] = Td[t];
        __syncthreads();
        ws[POWJ_OFF + sq * 64 + t] = (float)Md[t];  // A^(40*2^sq)
    }
}

// ---------------------------------------------------------------------------
__device__ __forceinline__ void step1(float& u, float* s,
                                      const float* c0, const float* c1,
                                      const float* c2, const float* A1,
                                      const float* A2) {
#pragma unroll
    for (int f = 0; f < NF; ++f) {
        float yv     = fmaf(c0[f], u, s[2 * f]);
        s[2 * f]     = fmaf(-A1[f], yv, fmaf(c1[f], u, s[2 * f + 1]));
        s[2 * f + 1] = fmaf(-A2[f], yv, c2[f] * u);
        u = yv;
    }
}

// Sparse (block-lower-triangular) matvec: o += T*p; T wave-uniform -> scalar.
__device__ __forceinline__ void matvec_acc_sp(float* o, const float* __restrict__ T,
                                              const float* p) {
#pragma unroll
    for (int r = 0; r < 8; ++r) {
        const int ncol = (r | 1) + 1;
#pragma unroll
        for (int c = 0; c < 8; ++c)
            if (c < ncol) o[r] = fmaf(T[r * 8 + c], p[c], o[r]);
    }
}

// ---------------------------------------------------------------------------
// One WAVE = one tile (2048 out + 512 warm-up). No __syncthreads anywhere.
// Wave-local LDS slice for the coalesced<->sequential transpose.
// ---------------------------------------------------------------------------
__global__ __launch_bounds__(TPB, 4) void biquad_k(const float* __restrict__ x,
                                                   const float* __restrict__ ws,
                                                   float* __restrict__ y) {
    __shared__ __align__(16) float ldsf[WPB * SLICE_F];
    const int lane = threadIdx.x & 63;
    const int wv   = threadIdx.x >> 6;
    float* sl = ldsf + wv * SLICE_F;

    // XCD-aware swizzle (4096 % 8 == 0 -> bijective)
    const int sb   = (blockIdx.x & 7) * (NBLK / 8) + (blockIdx.x >> 3);
    const int g    = sb * WPB + wv;
    const int row  = g >> 8;          // g / TPR
    const int tpos = g & (TPR - 1);   // g % TPR

    float c0[NF], c1[NF], c2[NF], A1[NF], A2[NF];
#pragma unroll
    for (int f = 0; f < NF; ++f) {
        c0[f] = ws[COEF_OFF + f * 5 + 0];
        c1[f] = ws[COEF_OFF + f * 5 + 1];
        c2[f] = ws[COEF_OFF + f * 5 + 2];
        A1[f] = ws[COEF_OFF + f * 5 + 3];
        A2[f] = ws[COEF_OFF + f * 5 + 4];
    }

    // ---- stage: coalesced global loads -> wave-private LDS slice ----
    const long base4 = (long)row * (Ln / 4) + (long)tpos * (OUT / 4) - (WU / 4);
    const float4* xg4 = (const float4*)x;
    float4 xv[10];
#pragma unroll
    for (int j = 0; j < 10; ++j) {
        const int n4 = j * 64 + lane;
        xv[j] = make_float4(0.f, 0.f, 0.f, 0.f);
        if (tpos > 0 || n4 >= (WU / 4)) xv[j] = xg4[base4 + n4];
    }
#pragma unroll
    for (int j = 0; j < 10; ++j) {
        const int gf = 4 * (j * 64 + lane);
        const int c  = gf / CPT;        // chunk (lane) owning this sample group
        const int i  = gf - CPT * c;
        float2* p = (float2*)(sl + CSTR * c + i);  // even idx -> 8B aligned
        p[0] = make_float2(xv[j].x, xv[j].y);
        p[1] = make_float2(xv[j].z, xv[j].w);
    }
    asm volatile("" ::: "memory");  // keep cross-lane LDS RAW order

    // ---- own chunk -> regs (stride 42: conflict-free b64) ----
    float y0[CPT];
    {
        const float2* cp = (const float2*)(sl + CSTR * lane);
#pragma unroll
        for (int i = 0; i < CPT / 2; ++i) {
            const float2 v = cp[i];
            y0[2 * i]     = v.x;
            y0[2 * i + 1] = v.y;
        }
    }
    asm volatile("" ::: "memory");

    // ---- pass 1: zero-state filter, y0 in regs, final state s ----
    float s[8];
#pragma unroll
    for (int r = 0; r < 8; ++r) s[r] = 0.f;
#pragma unroll
    for (int i = 0; i < CPT; ++i) {
        float u = y0[i];
        step1(u, s, c0, c1, c2, A1, A2);
        y0[i] = u;
    }

    // ---- intra-wave affine Kogge-Stone over 64 chunks ----
    const float* __restrict__ mats = ws + POWJ_OFF;
    float v8[8];
#pragma unroll
    for (int r = 0; r < 8; ++r) v8[r] = s[r];
#pragma unroll
    for (int j = 0; j < 6; ++j) {
        const int st = 1 << j;
        float p[8];
#pragma unroll
        for (int r = 0; r < 8; ++r) p[r] = __shfl_up(v8[r], st, 64);
        if (lane >= st) matvec_acc_sp(v8, mats + j * 64, p);
    }

    // ---- entry state delta = v8[lane-1] (tile entry is exactly 0) ----
    float dlt[8];
#pragma unroll
    for (int r = 0; r < 8; ++r) {
        const float pv = __shfl_up(v8[r], 1, 64);
        dlt[r] = (lane > 0) ? pv : 0.f;
    }

    // ---- correction: y_n = y0_n + w_n . delta (w rows scalar-loaded) ----
    const float* __restrict__ wsq = ws + WSEQ_OFF;
#pragma unroll
    for (int i = 0; i < CPT; ++i) {
        float a = 0.f;
#pragma unroll
        for (int k = 0; k < 8; ++k) a = fmaf(wsq[8 * i + k], dlt[k], a);
        y0[i] += a;
    }

    // ---- y regs -> LDS slice ----
    {
        float2* cp = (float2*)(sl + CSTR * lane);
#pragma unroll
        for (int i = 0; i < CPT / 2; ++i)
            cp[i] = make_float2(y0[2 * i], y0[2 * i + 1]);
    }
    asm volatile("" ::: "memory");

    // ---- coalesced store of output region (skip warm-up prefix) ----
    float4* yg4 = (float4*)y;
    const long obase4 = (long)row * (Ln / 4) + (long)tpos * (OUT / 4);
#pragma unroll
    for (int k = 0; k < 8; ++k) {
        const int n4 = (WU / 4) + k * 64 + lane;  // [128, 640)
        const int gf = 4 * n4;
        const int c  = gf / CPT;
        const int i  = gf - CPT * c;
        const float2* p = (const float2*)(sl + CSTR * c + i);
        const float2 a = p[0];
        const float2 b = p[1];
        yg4[obase4 + (n4 - WU / 4)] = make_float4(a.x, a.y, b.x, b.y);
    }
}

// ---------------------------------------------------------------------------
extern "C" void kernel_launch(void* const* d_in, const int* in_sizes, int n_in,
                              void* d_out, int out_size, void* d_ws, size_t ws_size,
                              hipStream_t stream) {
    const float* x  = (const float*)d_in[0];
    const float* lr = (const float*)d_in[1];
    const float* ra = (const float*)d_in[2];
    const float* b0 = (const float*)d_in[3];
    const float* b1 = (const float*)d_in[4];
    const float* b2 = (const float*)d_in[5];
    float* y  = (float*)d_out;
    float* ws = (float*)d_ws;

    precompute_k<<<dim3(1), dim3(64), 0, stream>>>(lr, ra, b0, b1, b2, ws);
    biquad_k<<<dim3(NBLK), dim3(TPB), 0, stream>>>(x, ws, y);
}